// Round 1
// 1473.295 us; speedup vs baseline: 1.4829x; 1.4829x over previous
//
#include <hip/hip_runtime.h>
#include <cmath>

typedef unsigned short u16;
typedef unsigned char u8;
typedef unsigned int u32;
typedef float f32x4 __attribute__((ext_vector_type(4)));
typedef int i32x4 __attribute__((ext_vector_type(4)));
typedef short s16x8 __attribute__((ext_vector_type(8)));
typedef u32 u32x4 __attribute__((ext_vector_type(4)));

#define D_MODEL 2048
#define HIDDEN  5461
#define HPAD    5504      // 86*64 = 43*128
#define WCNT    11184128  // HIDDEN*D_MODEL
#define XSCALE  4096.0f

// ---- bf16 round-to-nearest-even ----
__device__ __forceinline__ u16 f2bf(float f) {
  union { float f; u32 u; } c; c.f = f;
  u32 u = c.u + 0x7fffu + ((c.u >> 16) & 1u);
  return (u16)(u >> 16);
}

// ---- async global->LDS, 16B per lane (linear dest -> bank-conflict-free) ----
__device__ __forceinline__ void async16(const void* g, void* l) {
  __builtin_amdgcn_global_load_lds(
      (const __attribute__((address_space(1))) unsigned int*)g,
      (__attribute__((address_space(3))) unsigned int*)l, 16, 0, 0);
}

__global__ void zero_sums_kernel(double* __restrict__ s) {
  if (threadIdx.x < 3) s[threadIdx.x] = 0.0;
}

// ---- |w| sum reduction in f64 (decision-boundary-grade precision) ----
__global__ void abssum_kernel(const float* __restrict__ w, long n, double* __restrict__ out) {
  long i0 = ((long)blockIdx.x * blockDim.x + threadIdx.x) * 4;
  long stride = (long)gridDim.x * blockDim.x * 4;
  double s = 0.0;
  for (long i = i0; i < n; i += stride) {
    float4 v = *(const float4*)(w + i);
    s += (double)fabsf(v.x) + (double)fabsf(v.y) + (double)fabsf(v.z) + (double)fabsf(v.w);
  }
#pragma unroll
  for (int off = 32; off > 0; off >>= 1) s += __shfl_down(s, off, 64);
  __shared__ double ls[4];
  int lane = threadIdx.x & 63, wv = threadIdx.x >> 6;
  if (lane == 0) ls[wv] = s;
  __syncthreads();
  if (threadIdx.x == 0) atomicAdd(out, ls[0] + ls[1] + ls[2] + ls[3]);
}

// ---- quantize w1/w3 [HIDDEN, 2048] -> ternary i8 staged [nt 0..85][kg 0..127][col 64][16] ----
__global__ void quant13_kernel(const float* __restrict__ w, const double* __restrict__ sum,
                               char* __restrict__ ws) {
  double s = *sum * (1.0 / (double)WCNT);
  int nt = blockIdx.x;                      // 0..85
  int c  = blockIdx.y * 256 + threadIdx.x;  // 0..8191
  int col = c & 63;
  int kg  = c >> 6;                         // 0..127
  int n = nt * 64 + col;
  u32x4 qv = {0u, 0u, 0u, 0u};
  if (n < HIDDEN) {
    const float* row = w + (long)n * D_MODEL + kg * 16;
#pragma unroll
    for (int q4 = 0; q4 < 4; ++q4) {
      float4 v = *(const float4*)(row + q4 * 4);
      float vv[4] = {v.x, v.y, v.z, v.w};
      u32 word = 0;
#pragma unroll
      for (int e = 0; e < 4; ++e) {
        int qi = (int)fmin(fmax(rint((double)vv[e] / s), -1.0), 1.0);
        word |= ((u32)(u8)(char)qi) << (8 * e);
      }
      qv[q4] = word;
    }
  }
  *(u32x4*)(ws + (long)nt * 131072 + ((long)kg * 64 + col) * 16) = qv;
}

// ---- quantize w2 [2048, HIDDEN] -> ternary bf16 staged [nt 0..15][kg 0..687][128][8] ----
__global__ void quant2_kernel(const float* __restrict__ w, const double* __restrict__ sum,
                              u16* __restrict__ ws) {
  double s = *sum * (1.0 / (double)WCNT);
  int nt = blockIdx.x;          // 0..15
  int kc = blockIdx.y;          // 0..85
  int nn = threadIdx.x & 127;
  int kl = threadIdx.x >> 7;
  int n = nt * 128 + nn;
  long base = (long)nt * 704512;
#pragma unroll
  for (int it = 0; it < 4; ++it) {
    int kgl = kl + it * 2;
    int kg = kc * 8 + kgl;
    s16x8 qv;
#pragma unroll
    for (int j = 0; j < 8; ++j) {
      int k = kg * 8 + j;
      float q = 0.f;
      if (k < HIDDEN) {
        float v = w[(long)n * HIDDEN + k];
        q = (float)fmin(fmax(rint((double)v / s), -1.0), 1.0);
      }
      qv[j] = (short)f2bf(q);
    }
    *(s16x8*)(ws + base + ((long)kg * 128 + nn) * 8) = qv;
  }
}

// ---- quantize x to i16 = hi8*256 + lo8, stored as two i8 planes in gemm1 tile layout
//      [mt 0..127][kg 0..127][row 0..127][16B] ----
__global__ void xquant_kernel(const float* __restrict__ x, u8* __restrict__ xhi,
                              u8* __restrict__ xlo) {
  int mt = blockIdx.x;                      // 0..127
  int c  = blockIdx.y * 256 + threadIdx.x;  // 0..16383
  int row = c & 127;
  int kg  = c >> 7;                         // 0..127
  const float* src = x + ((long)mt * 128 + row) * D_MODEL + kg * 16;
  u32x4 hv, lv;
#pragma unroll
  for (int q4 = 0; q4 < 4; ++q4) {
    float4 v = *(const float4*)(src + q4 * 4);
    float vv[4] = {v.x, v.y, v.z, v.w};
    u32 hw = 0, lw = 0;
#pragma unroll
    for (int e = 0; e < 4; ++e) {
      float f = fminf(fmaxf(vv[e] * XSCALE, -32639.f), 32639.f);
      int tt = (int)rintf(f) + 128;          // xi = (tt>>8)*256 + ((tt&0xFF)-128), exact
      hw |= ((u32)((tt >> 8) & 0xFF)) << (8 * e);
      lw |= ((u32)((tt ^ 0x80) & 0xFF)) << (8 * e);
    }
    hv[q4] = hw; lv[q4] = lw;
  }
  long o = (long)mt * 262144 + ((long)kg * 128 + row) * 16;
  *(u32x4*)(xhi + o) = hv;
  *(u32x4*)(xlo + o) = lv;
}

// ---- GEMM1: dual-i8 exact int GEMM, x{hi,lo} x {w1q,w3q} -> g = silu(h1)*h3 -> gs bf16
//      block tile 128x64, 4 waves of 64x32, all staging via global_load_lds ----
__global__ __launch_bounds__(256, 2)
void gemm1_kernel(const u8* __restrict__ xhi, const u8* __restrict__ xlo,
                  const char* __restrict__ w1s, const char* __restrict__ w3s,
                  const double* __restrict__ sums, u16* __restrict__ gs, int mt0) {
  __shared__ alignas(16) u8 Ahi[8192];   // [kgl 0..3][row 0..127][16]
  __shared__ alignas(16) u8 Alo[8192];
  __shared__ alignas(16) u8 B1s[4096];   // [kgl 0..3][col 0..63][16]
  __shared__ alignas(16) u8 B3s[4096];
  const int mtl = blockIdx.x;            // 0..63 (local M tile within pass)
  const int nt  = blockIdx.y;            // 0..85
  const int mtg = mt0 + mtl;
  const int t = threadIdx.x;
  const int lane = t & 63, wave = t >> 6;
  const int wm = wave >> 1, wn = wave & 1;
  const int quad = lane >> 4;
  const int rowA = wm * 64 + (lane & 15);
  const int rowB = wn * 32 + (lane & 15);

  i32x4 a1h[4][2], a1l[4][2], a3h[4][2], a3l[4][2];
#pragma unroll
  for (int i = 0; i < 4; ++i)
#pragma unroll
    for (int j = 0; j < 2; ++j) {
      a1h[i][j] = {0, 0, 0, 0}; a1l[i][j] = {0, 0, 0, 0};
      a3h[i][j] = {0, 0, 0, 0}; a3l[i][j] = {0, 0, 0, 0};
    }

  const u8* Ah = xhi + (long)mtg * 262144 + t * 16;
  const u8* Al = xlo + (long)mtg * 262144 + t * 16;
  const char* B1 = w1s + (long)nt * 131072 + t * 16;
  const char* B3 = w3s + (long)nt * 131072 + t * 16;

  for (int c = 0; c < 32; ++c) {
    async16(Ah + c * 8192,        &Ahi[t * 16]);
    async16(Ah + c * 8192 + 4096, &Ahi[4096 + t * 16]);
    async16(Al + c * 8192,        &Alo[t * 16]);
    async16(Al + c * 8192 + 4096, &Alo[4096 + t * 16]);
    async16(B1 + c * 4096, &B1s[t * 16]);
    async16(B3 + c * 4096, &B3s[t * 16]);
    __syncthreads();
    i32x4 b1f[2], b3f[2], ah[4], al[4];
#pragma unroll
    for (int j = 0; j < 2; ++j) {
      b1f[j] = *(const i32x4*)&B1s[quad * 1024 + (rowB + j * 16) * 16];
      b3f[j] = *(const i32x4*)&B3s[quad * 1024 + (rowB + j * 16) * 16];
    }
#pragma unroll
    for (int i = 0; i < 4; ++i) {
      ah[i] = *(const i32x4*)&Ahi[quad * 2048 + (rowA + i * 16) * 16];
      al[i] = *(const i32x4*)&Alo[quad * 2048 + (rowA + i * 16) * 16];
    }
#pragma unroll
    for (int i = 0; i < 4; ++i)
#pragma unroll
      for (int j = 0; j < 2; ++j) {
        a1h[i][j] = __builtin_amdgcn_mfma_i32_16x16x64_i8(ah[i], b1f[j], a1h[i][j], 0, 0, 0);
        a1l[i][j] = __builtin_amdgcn_mfma_i32_16x16x64_i8(al[i], b1f[j], a1l[i][j], 0, 0, 0);
        a3h[i][j] = __builtin_amdgcn_mfma_i32_16x16x64_i8(ah[i], b3f[j], a3h[i][j], 0, 0, 0);
        a3l[i][j] = __builtin_amdgcn_mfma_i32_16x16x64_i8(al[i], b3f[j], a3l[i][j], 0, 0, 0);
      }
    __syncthreads();
  }

  const float sc1 = (float)(sums[0] * (1.0 / (double)WCNT)) / XSCALE;
  const float sc3 = (float)(sums[1] * (1.0 / (double)WCNT)) / XSCALE;
  u16* gb = gs + (long)mtl * 704512;
#pragma unroll
  for (int i = 0; i < 4; ++i) {
#pragma unroll
    for (int j = 0; j < 2; ++j) {
      const int h = nt * 64 + wn * 32 + j * 16 + (lane & 15);
      const int kg2 = h >> 3, jj = h & 7;
#pragma unroll
      for (int rr = 0; rr < 4; ++rr) {
        const int mm = wm * 64 + i * 16 + quad * 4 + rr;
        float h1 = (float)(a1h[i][j][rr] * 256 + a1l[i][j][rr]) * sc1;
        float h3 = (float)(a3h[i][j][rr] * 256 + a3l[i][j][rr]) * sc3;
        float g = (h1 / (1.0f + expf(-h1))) * h3;
        gb[((long)kg2 * 128 + mm) * 8 + jj] = f2bf(g);
      }
    }
  }
}

// ---- GEMM2: out = s2 * (g_bf16 . w2q^T), K = 5504 ----
__global__ __launch_bounds__(256, 2)
void gemm2_kernel(const u16* __restrict__ gs, const u16* __restrict__ w2s,
                  const double* __restrict__ sums, float* __restrict__ out) {
  __shared__ alignas(16) u16 As[8192];
  __shared__ alignas(16) u16 Bs[8192];
  const int mt = blockIdx.x, nt = blockIdx.y;
  const int t = threadIdx.x;
  const int lane = t & 63, wave = t >> 6;
  const int wm = wave >> 1, wn = wave & 1;
  const int quad = lane >> 4;
  const int rowA = wm * 64 + (lane & 15);
  const int rowB = wn * 64 + (lane & 15);

  f32x4 acc[4][4];
#pragma unroll
  for (int i = 0; i < 4; ++i)
#pragma unroll
    for (int j = 0; j < 4; ++j) acc[i][j] = {0.f, 0.f, 0.f, 0.f};

  const u16* Ab = gs  + (long)mt * 704512 + t * 8;
  const u16* Bb = w2s + (long)nt * 704512 + t * 8;

  for (int c = 0; c < 86; ++c) {
    const u16* ag = Ab + (long)c * 8192;
    const u16* bg = Bb + (long)c * 8192;
#pragma unroll
    for (int j = 0; j < 4; ++j) {
      async16(ag + j * 2048, &As[t * 8 + j * 2048]);
      async16(bg + j * 2048, &Bs[t * 8 + j * 2048]);
    }
    __syncthreads();
#pragma unroll
    for (int ks = 0; ks < 2; ++ks) {
      const int kg = ks * 4 + quad;
      s16x8 af[4], bf[4];
#pragma unroll
      for (int i = 0; i < 4; ++i)
        af[i] = *(const s16x8*)&As[kg * 1024 + (rowA + i * 16) * 8];
#pragma unroll
      for (int j = 0; j < 4; ++j)
        bf[j] = *(const s16x8*)&Bs[kg * 1024 + (rowB + j * 16) * 8];
#pragma unroll
      for (int i = 0; i < 4; ++i)
#pragma unroll
        for (int j = 0; j < 4; ++j)
          acc[i][j] = __builtin_amdgcn_mfma_f32_16x16x32_bf16(af[i], bf[j], acc[i][j], 0, 0, 0);
    }
    __syncthreads();
  }

  const float s2 = (float)(sums[2] * (1.0 / (double)WCNT));
#pragma unroll
  for (int i = 0; i < 4; ++i) {
    const int r0 = wm * 64 + i * 16 + quad * 4;
#pragma unroll
    for (int j = 0; j < 4; ++j) {
      const int d = nt * 128 + wn * 64 + j * 16 + (lane & 15);
#pragma unroll
      for (int rr = 0; rr < 4; ++rr) {
        const long m = (long)mt * 128 + r0 + rr;
        out[m * D_MODEL + d] = acc[i][j][rr] * s2;
      }
    }
  }
}

extern "C" void kernel_launch(void* const* d_in, const int* in_sizes, int n_in,
                              void* d_out, int out_size, void* d_ws, size_t ws_size,
                              hipStream_t stream) {
  (void)in_sizes; (void)n_in; (void)out_size; (void)ws_size;
  const float* x  = (const float*)d_in[0];
  const float* w1 = (const float*)d_in[1];
  const float* w3 = (const float*)d_in[2];
  const float* w2 = (const float*)d_in[3];
  float* out = (float*)d_out;

  // workspace layout (total ~193 MiB, < 236.5 MiB previously proven):
  //   sums: 3 f64 (256 B slot)
  //   w1s/w3s: i8 ternary [86][128][64][16]  = 11,272,192 B each
  //   w2s:     bf16 [16][688][128][8]        = 22,544,384 B
  //   xhi/xlo: i8 planes [128][128][128][16] = 33,554,432 B each
  //   gs:      bf16 HALF-M [64][688][128][8] = 90,177,536 B  (reused across 2 passes)
  char* ws = (char*)d_ws;
  double* sums = (double*)ws;
  char* w1s = ws + 256;
  char* w3s = w1s + 11272192L;
  u16*  w2s = (u16*)(w3s + 11272192L);
  u8*   xhi = (u8*)(w3s + 11272192L + 22544384L);
  u8*   xlo = xhi + 33554432L;
  u16*  gs  = (u16*)(xlo + 33554432L);

  zero_sums_kernel<<<1, 64, 0, stream>>>(sums);
  abssum_kernel<<<1024, 256, 0, stream>>>(w1, (long)WCNT, sums + 0);
  abssum_kernel<<<1024, 256, 0, stream>>>(w3, (long)WCNT, sums + 1);
  abssum_kernel<<<1024, 256, 0, stream>>>(w2, (long)WCNT, sums + 2);

  quant13_kernel<<<dim3(86, 32), 256, 0, stream>>>(w1, sums + 0, w1s);
  quant13_kernel<<<dim3(86, 32), 256, 0, stream>>>(w3, sums + 1, w3s);
  quant2_kernel<<<dim3(16, 86), 256, 0, stream>>>(w2, sums + 2, w2s);
  xquant_kernel<<<dim3(128, 64), 256, 0, stream>>>(x, xhi, xlo);

  for (int pass = 0; pass < 2; ++pass) {
    gemm1_kernel<<<dim3(64, 86), 256, 0, stream>>>(xhi, xlo, w1s, w3s, sums, gs, pass * 64);
    gemm2_kernel<<<dim3(64, 16), 256, 0, stream>>>(gs, w2s, sums,
                                                   out + (long)pass * 64 * 128 * D_MODEL);
  }
}

// Round 2
// 1345.178 us; speedup vs baseline: 1.6241x; 1.0952x over previous
//
#include <hip/hip_runtime.h>
#include <cmath>

typedef unsigned short u16;
typedef unsigned char u8;
typedef unsigned int u32;
typedef float f32x4 __attribute__((ext_vector_type(4)));
typedef int i32x4 __attribute__((ext_vector_type(4)));
typedef short s16x8 __attribute__((ext_vector_type(8)));
typedef u32 u32x4 __attribute__((ext_vector_type(4)));

#define D_MODEL 2048
#define HIDDEN  5461
#define HPAD    5504      // 86*64 = 43*128
#define WCNT    11184128  // HIDDEN*D_MODEL
#define XSCALE  4096.0f

// ---- bf16 round-to-nearest-even ----
__device__ __forceinline__ u16 f2bf(float f) {
  union { float f; u32 u; } c; c.f = f;
  u32 u = c.u + 0x7fffu + ((c.u >> 16) & 1u);
  return (u16)(u >> 16);
}

// ---- async global->LDS, 16B per lane (linear dest -> bank-conflict-free) ----
__device__ __forceinline__ void async16(const void* g, void* l) {
  __builtin_amdgcn_global_load_lds(
      (const __attribute__((address_space(1))) unsigned int*)g,
      (__attribute__((address_space(3))) unsigned int*)l, 16, 0, 0);
}

__global__ void zero_sums_kernel(double* __restrict__ s) {
  if (threadIdx.x < 3) s[threadIdx.x] = 0.0;
}

// ---- |w| sum reduction in f64 (decision-boundary-grade precision) ----
__global__ void abssum_kernel(const float* __restrict__ w, long n, double* __restrict__ out) {
  long i0 = ((long)blockIdx.x * blockDim.x + threadIdx.x) * 4;
  long stride = (long)gridDim.x * blockDim.x * 4;
  double s = 0.0;
  for (long i = i0; i < n; i += stride) {
    float4 v = *(const float4*)(w + i);
    s += (double)fabsf(v.x) + (double)fabsf(v.y) + (double)fabsf(v.z) + (double)fabsf(v.w);
  }
#pragma unroll
  for (int off = 32; off > 0; off >>= 1) s += __shfl_down(s, off, 64);
  __shared__ double ls[4];
  int lane = threadIdx.x & 63, wv = threadIdx.x >> 6;
  if (lane == 0) ls[wv] = s;
  __syncthreads();
  if (threadIdx.x == 0) atomicAdd(out, ls[0] + ls[1] + ls[2] + ls[3]);
}

// ---- quantize w1/w3 [HIDDEN, 2048] -> ternary i8 staged [nt 0..85][kg 0..127][col 64][16] ----
__global__ void quant13_kernel(const float* __restrict__ w, const double* __restrict__ sum,
                               char* __restrict__ ws) {
  double s = *sum * (1.0 / (double)WCNT);
  int nt = blockIdx.x;                      // 0..85
  int c  = blockIdx.y * 256 + threadIdx.x;  // 0..8191
  int col = c & 63;
  int kg  = c >> 6;                         // 0..127
  int n = nt * 64 + col;
  u32x4 qv = {0u, 0u, 0u, 0u};
  if (n < HIDDEN) {
    const float* row = w + (long)n * D_MODEL + kg * 16;
#pragma unroll
    for (int q4 = 0; q4 < 4; ++q4) {
      float4 v = *(const float4*)(row + q4 * 4);
      float vv[4] = {v.x, v.y, v.z, v.w};
      u32 word = 0;
#pragma unroll
      for (int e = 0; e < 4; ++e) {
        int qi = (int)fmin(fmax(rint((double)vv[e] / s), -1.0), 1.0);
        word |= ((u32)(u8)(char)qi) << (8 * e);
      }
      qv[q4] = word;
    }
  }
  *(u32x4*)(ws + (long)nt * 131072 + ((long)kg * 64 + col) * 16) = qv;
}

// ---- quantize w2 [2048, HIDDEN] -> ternary bf16 staged [nt 0..15][kg 0..687][128][8] ----
__global__ void quant2_kernel(const float* __restrict__ w, const double* __restrict__ sum,
                              u16* __restrict__ ws) {
  double s = *sum * (1.0 / (double)WCNT);
  int nt = blockIdx.x;          // 0..15
  int kc = blockIdx.y;          // 0..85
  int nn = threadIdx.x & 127;
  int kl = threadIdx.x >> 7;
  int n = nt * 128 + nn;
  long base = (long)nt * 704512;
#pragma unroll
  for (int it = 0; it < 4; ++it) {
    int kgl = kl + it * 2;
    int kg = kc * 8 + kgl;
    s16x8 qv;
#pragma unroll
    for (int j = 0; j < 8; ++j) {
      int k = kg * 8 + j;
      float q = 0.f;
      if (k < HIDDEN) {
        float v = w[(long)n * HIDDEN + k];
        q = (float)fmin(fmax(rint((double)v / s), -1.0), 1.0);
      }
      qv[j] = (short)f2bf(q);
    }
    *(s16x8*)(ws + base + ((long)kg * 128 + nn) * 8) = qv;
  }
}

// ---- quantize x to i16 = hi8*256 + lo8, stored as two i8 planes in gemm1 tile layout
//      [mt 0..127][kg 0..127][row 0..127][16B] ----
__global__ void xquant_kernel(const float* __restrict__ x, u8* __restrict__ xhi,
                              u8* __restrict__ xlo) {
  int mt = blockIdx.x;                      // 0..127
  int c  = blockIdx.y * 256 + threadIdx.x;  // 0..16383
  int row = c & 127;
  int kg  = c >> 7;                         // 0..127
  const float* src = x + ((long)mt * 128 + row) * D_MODEL + kg * 16;
  u32x4 hv, lv;
#pragma unroll
  for (int q4 = 0; q4 < 4; ++q4) {
    float4 v = *(const float4*)(src + q4 * 4);
    float vv[4] = {v.x, v.y, v.z, v.w};
    u32 hw = 0, lw = 0;
#pragma unroll
    for (int e = 0; e < 4; ++e) {
      float f = fminf(fmaxf(vv[e] * XSCALE, -32639.f), 32639.f);
      int tt = (int)rintf(f) + 128;          // xi = (tt>>8)*256 + ((tt&0xFF)-128), exact
      hw |= ((u32)((tt >> 8) & 0xFF)) << (8 * e);
      lw |= ((u32)((tt ^ 0x80) & 0xFF)) << (8 * e);
    }
    hv[q4] = hw; lv[q4] = lw;
  }
  long o = (long)mt * 262144 + ((long)kg * 128 + row) * 16;
  *(u32x4*)(xhi + o) = hv;
  *(u32x4*)(xlo + o) = lv;
}

// ---- GEMM1: dual-i8 exact int GEMM, triple-buffered LDS, counted vmcnt, 1 barrier/K-step.
//      block tile 128x64, 4 waves of 64x32. ----
__global__ __launch_bounds__(256, 2)
void gemm1_kernel(const u8* __restrict__ xhi, const u8* __restrict__ xlo,
                  const char* __restrict__ w1s, const char* __restrict__ w3s,
                  const double* __restrict__ sums, u16* __restrict__ gs, int mt0) {
  // per buffer (24576 B): Ahi@0 [kgl4][row128][16], Alo@8192, B1@16384 [kgl4][col64][16], B3@20480
  __shared__ alignas(16) u8 L[3 * 24576];
  const int mtl = blockIdx.x;            // 0..63 (local M tile within pass)
  const int nt  = blockIdx.y;            // 0..85
  const int mtg = mt0 + mtl;
  const int t = threadIdx.x;
  const int lane = t & 63, wave = t >> 6;
  const int wm = wave >> 1, wn = wave & 1;
  const int quad = lane >> 4;
  const int rowA = wm * 64 + (lane & 15);
  const int rowB = wn * 32 + (lane & 15);

  i32x4 a1h[4][2], a1l[4][2], a3h[4][2], a3l[4][2];
#pragma unroll
  for (int i = 0; i < 4; ++i)
#pragma unroll
    for (int j = 0; j < 2; ++j) {
      a1h[i][j] = {0, 0, 0, 0}; a1l[i][j] = {0, 0, 0, 0};
      a3h[i][j] = {0, 0, 0, 0}; a3l[i][j] = {0, 0, 0, 0};
    }

  const u8* Ah = xhi + (long)mtg * 262144 + t * 16;
  const u8* Al = xlo + (long)mtg * 262144 + t * 16;
  const char* B1 = w1s + (long)nt * 131072 + t * 16;
  const char* B3 = w3s + (long)nt * 131072 + t * 16;

#define STAGE1(buf, c) do {                                      \
    u8* Lb_ = L + (buf) * 24576;                                 \
    async16(Ah + (c) * 8192,        Lb_ + t * 16);               \
    async16(Ah + (c) * 8192 + 4096, Lb_ + 4096 + t * 16);        \
    async16(Al + (c) * 8192,        Lb_ + 8192 + t * 16);        \
    async16(Al + (c) * 8192 + 4096, Lb_ + 12288 + t * 16);       \
    async16(B1 + (c) * 4096,        Lb_ + 16384 + t * 16);       \
    async16(B3 + (c) * 4096,        Lb_ + 20480 + t * 16);       \
  } while (0)

  STAGE1(0, 0);
  int cur = 0;
  for (int c = 0; c < 32; ++c) {
    int nb = cur + 1; if (nb == 3) nb = 0;
    if (c < 31) {
      STAGE1(nb, c + 1);
      // wait only the OLDEST 6 loads (tile c); tile c+1's 6 stay in flight across barrier
      asm volatile("s_waitcnt vmcnt(6)" ::: "memory");
    } else {
      asm volatile("s_waitcnt vmcnt(0)" ::: "memory");
    }
    __builtin_amdgcn_s_barrier();
    const u8* Lb = L + cur * 24576;
    i32x4 b1f[2], b3f[2], ah[4], al[4];
#pragma unroll
    for (int j = 0; j < 2; ++j) {
      b1f[j] = *(const i32x4*)&Lb[16384 + quad * 1024 + (rowB + j * 16) * 16];
      b3f[j] = *(const i32x4*)&Lb[20480 + quad * 1024 + (rowB + j * 16) * 16];
    }
#pragma unroll
    for (int i = 0; i < 4; ++i) {
      ah[i] = *(const i32x4*)&Lb[quad * 2048 + (rowA + i * 16) * 16];
      al[i] = *(const i32x4*)&Lb[8192 + quad * 2048 + (rowA + i * 16) * 16];
    }
    __builtin_amdgcn_s_setprio(1);
#pragma unroll
    for (int i = 0; i < 4; ++i)
#pragma unroll
      for (int j = 0; j < 2; ++j) {
        a1h[i][j] = __builtin_amdgcn_mfma_i32_16x16x64_i8(ah[i], b1f[j], a1h[i][j], 0, 0, 0);
        a1l[i][j] = __builtin_amdgcn_mfma_i32_16x16x64_i8(al[i], b1f[j], a1l[i][j], 0, 0, 0);
        a3h[i][j] = __builtin_amdgcn_mfma_i32_16x16x64_i8(ah[i], b3f[j], a3h[i][j], 0, 0, 0);
        a3l[i][j] = __builtin_amdgcn_mfma_i32_16x16x64_i8(al[i], b3f[j], a3l[i][j], 0, 0, 0);
      }
    __builtin_amdgcn_s_setprio(0);
    cur = nb;
  }
#undef STAGE1

  const float sc1 = (float)(sums[0] * (1.0 / (double)WCNT)) / XSCALE;
  const float sc3 = (float)(sums[1] * (1.0 / (double)WCNT)) / XSCALE;
  u16* gb = gs + (long)mtl * 704512;
#pragma unroll
  for (int i = 0; i < 4; ++i) {
#pragma unroll
    for (int j = 0; j < 2; ++j) {
      const int h = nt * 64 + wn * 32 + j * 16 + (lane & 15);
      const int kg2 = h >> 3, jj = h & 7;
#pragma unroll
      for (int rr = 0; rr < 4; ++rr) {
        const int mm = wm * 64 + i * 16 + quad * 4 + rr;
        float h1 = (float)(a1h[i][j][rr] * 256 + a1l[i][j][rr]) * sc1;
        float h3 = (float)(a3h[i][j][rr] * 256 + a3l[i][j][rr]) * sc3;
        float g = (h1 / (1.0f + expf(-h1))) * h3;
        gb[((long)kg2 * 128 + mm) * 8 + jj] = f2bf(g);
      }
    }
  }
}

// ---- GEMM2: out = s2 * (g_bf16 . w2q^T), K = 5504, BK=32, triple-buffered, counted vmcnt ----
__global__ __launch_bounds__(256, 2)
void gemm2_kernel(const u16* __restrict__ gs, const u16* __restrict__ w2s,
                  const double* __restrict__ sums, float* __restrict__ out) {
  // per buffer (8192 u16 = 16 KB): A@0 [kg4][row128][8], B@4096 [kg4][col128][8]
  __shared__ alignas(16) u16 L[3 * 8192];
  const int mt = blockIdx.x, nt = blockIdx.y;
  const int t = threadIdx.x;
  const int lane = t & 63, wave = t >> 6;
  const int wm = wave >> 1, wn = wave & 1;
  const int quad = lane >> 4;
  const int rowA = wm * 64 + (lane & 15);
  const int rowB = wn * 64 + (lane & 15);

  f32x4 acc[4][4];
#pragma unroll
  for (int i = 0; i < 4; ++i)
#pragma unroll
    for (int j = 0; j < 4; ++j) acc[i][j] = {0.f, 0.f, 0.f, 0.f};

  const u16* Ab = gs  + (long)mt * 704512 + t * 8;
  const u16* Bb = w2s + (long)nt * 704512 + t * 8;

#define STAGE2(buf, c) do {                                      \
    u16* Lb_ = L + (buf) * 8192;                                 \
    async16(Ab + (c) * 4096,        Lb_ + t * 8);                \
    async16(Ab + (c) * 4096 + 2048, Lb_ + 2048 + t * 8);         \
    async16(Bb + (c) * 4096,        Lb_ + 4096 + t * 8);         \
    async16(Bb + (c) * 4096 + 2048, Lb_ + 6144 + t * 8);         \
  } while (0)

  STAGE2(0, 0);
  int cur = 0;
  for (int c = 0; c < 172; ++c) {
    int nb = cur + 1; if (nb == 3) nb = 0;
    if (c < 171) {
      STAGE2(nb, c + 1);
      asm volatile("s_waitcnt vmcnt(4)" ::: "memory");
    } else {
      asm volatile("s_waitcnt vmcnt(0)" ::: "memory");
    }
    __builtin_amdgcn_s_barrier();
    const u16* Lb = L + cur * 8192;
    s16x8 af[4], bf[4];
#pragma unroll
    for (int i = 0; i < 4; ++i)
      af[i] = *(const s16x8*)&Lb[quad * 1024 + (rowA + i * 16) * 8];
#pragma unroll
    for (int j = 0; j < 4; ++j)
      bf[j] = *(const s16x8*)&Lb[4096 + quad * 1024 + (rowB + j * 16) * 8];
    __builtin_amdgcn_s_setprio(1);
#pragma unroll
    for (int i = 0; i < 4; ++i)
#pragma unroll
      for (int j = 0; j < 4; ++j)
        acc[i][j] = __builtin_amdgcn_mfma_f32_16x16x32_bf16(af[i], bf[j], acc[i][j], 0, 0, 0);
    __builtin_amdgcn_s_setprio(0);
    cur = nb;
  }
#undef STAGE2

  const float s2 = (float)(sums[2] * (1.0 / (double)WCNT));
#pragma unroll
  for (int i = 0; i < 4; ++i) {
    const int r0 = wm * 64 + i * 16 + quad * 4;
#pragma unroll
    for (int j = 0; j < 4; ++j) {
      const int d = nt * 128 + wn * 64 + j * 16 + (lane & 15);
#pragma unroll
      for (int rr = 0; rr < 4; ++rr) {
        const long m = (long)mt * 128 + r0 + rr;
        out[m * D_MODEL + d] = acc[i][j][rr] * s2;
      }
    }
  }
}

extern "C" void kernel_launch(void* const* d_in, const int* in_sizes, int n_in,
                              void* d_out, int out_size, void* d_ws, size_t ws_size,
                              hipStream_t stream) {
  (void)in_sizes; (void)n_in; (void)out_size; (void)ws_size;
  const float* x  = (const float*)d_in[0];
  const float* w1 = (const float*)d_in[1];
  const float* w3 = (const float*)d_in[2];
  const float* w2 = (const float*)d_in[3];
  float* out = (float*)d_out;

  // workspace layout (total ~193 MiB):
  //   sums: 3 f64 (256 B slot)
  //   w1s/w3s: i8 ternary [86][128][64][16]  = 11,272,192 B each
  //   w2s:     bf16 [16][688][128][8]        = 22,544,384 B
  //   xhi/xlo: i8 planes [128][128][128][16] = 33,554,432 B each
  //   gs:      bf16 HALF-M [64][688][128][8] = 90,177,536 B  (reused across 2 passes)
  char* ws = (char*)d_ws;
  double* sums = (double*)ws;
  char* w1s = ws + 256;
  char* w3s = w1s + 11272192L;
  u16*  w2s = (u16*)(w3s + 11272192L);
  u8*   xhi = (u8*)(w3s + 11272192L + 22544384L);
  u8*   xlo = xhi + 33554432L;
  u16*  gs  = (u16*)(xlo + 33554432L);

  zero_sums_kernel<<<1, 64, 0, stream>>>(sums);
  abssum_kernel<<<1024, 256, 0, stream>>>(w1, (long)WCNT, sums + 0);
  abssum_kernel<<<1024, 256, 0, stream>>>(w3, (long)WCNT, sums + 1);
  abssum_kernel<<<1024, 256, 0, stream>>>(w2, (long)WCNT, sums + 2);

  quant13_kernel<<<dim3(86, 32), 256, 0, stream>>>(w1, sums + 0, w1s);
  quant13_kernel<<<dim3(86, 32), 256, 0, stream>>>(w3, sums + 1, w3s);
  quant2_kernel<<<dim3(16, 86), 256, 0, stream>>>(w2, sums + 2, w2s);
  xquant_kernel<<<dim3(128, 64), 256, 0, stream>>>(x, xhi, xlo);

  for (int pass = 0; pass < 2; ++pass) {
    gemm1_kernel<<<dim3(64, 86), 256, 0, stream>>>(xhi, xlo, w1s, w3s, sums, gs, pass * 64);
    gemm2_kernel<<<dim3(64, 16), 256, 0, stream>>>(gs, w2s, sums,
                                                   out + (long)pass * 64 * 128 * D_MODEL);
  }
}